// Round 7
// baseline (2373.474 us; speedup 1.0000x reference)
//
#include <hip/hip_runtime.h>
#include <stdint.h>
#include <stddef.h>

#define M_TOK 8192
#define N_OUT 4096
#define K_IN  4096
#define R_LORA 16

// ---- 256x256 4-phase/tile GEMM geometry ----
#define BM 256
#define BN 256
#define BK 64
#define NT (K_IN / BK)          // 64 K-tiles

// prologue grids: pure casts (weff eliminated via lora-on-output identity)
#define CASTX_BLOCKS ((M_TOK * K_IN) / (8 * 256))   // 16384
#define CASTW_BLOCKS ((N_OUT * K_IN) / (8 * 256))   // 8192
#define LORA_BLOCKS  (M_TOK / 8)                    // 1024
#define T_BYTES ((size_t)M_TOK * R_LORA * sizeof(float))  // 512 KB

typedef __bf16 bf16_t;
typedef __bf16 bf16x4 __attribute__((ext_vector_type(4)));
typedef __bf16 bf16x8 __attribute__((ext_vector_type(8)));
typedef float floatx4 __attribute__((ext_vector_type(4)));

// async global->LDS, 16B per lane. LDS dest must be wave-uniform base; HW adds lane*16.
__device__ inline void async_copy16(const bf16_t* g, bf16_t* l) {
  __builtin_amdgcn_global_load_lds(
      (__attribute__((address_space(1))) void*)(uintptr_t)(const void*)g,
      (__attribute__((address_space(3))) void*)l,
      16, 0, 0);
}

#define BAR()   __builtin_amdgcn_s_barrier()
#define VMCNT4  asm volatile("s_waitcnt vmcnt(4)" ::: "memory")
#define VMCNT2  asm volatile("s_waitcnt vmcnt(2)" ::: "memory")
#define VMCNT0  asm volatile("s_waitcnt vmcnt(0)" ::: "memory")

// ---------------- prologue pass 1: cast x AND W -> bf16 (pure streaming) ----------------
__global__ __launch_bounds__(256) void prep_cast(const float* __restrict__ x,
                                                 bf16_t* __restrict__ xb,
                                                 const float* __restrict__ W,
                                                 bf16_t* __restrict__ wb) {
  const int b = blockIdx.x;
  const float* src;
  bf16_t* dst;
  size_t t;
  if (b < CASTX_BLOCKS) {
    src = x;  dst = xb;  t = (size_t)b * 256 + threadIdx.x;
  } else {
    src = W;  dst = wb;  t = (size_t)(b - CASTX_BLOCKS) * 256 + threadIdx.x;
  }
  const float4* sp = (const float4*)src + t * 2;
  float4 a0 = sp[0];
  float4 a1 = sp[1];
  bf16x8 v;
  v[0] = (bf16_t)a0.x; v[1] = (bf16_t)a0.y; v[2] = (bf16_t)a0.z; v[3] = (bf16_t)a0.w;
  v[4] = (bf16_t)a1.x; v[5] = (bf16_t)a1.y; v[6] = (bf16_t)a1.z; v[7] = (bf16_t)a1.w;
  *(bf16x8*)(dst + t * 8) = v;
}

// ---------------- prologue pass 2: t[m,r] = scale * sum_k x[m,k] * lA[r,k] ----------------
// 8 m-rows per block: lA slice loaded once per thread, reused across 8 rows.
// Thread (r = tid&15, kcn = tid>>4) covers k in [kcn*256, kcn*256+256).
__global__ __launch_bounds__(256) void lora_xa8(const float* __restrict__ x,
                                                const float* __restrict__ lA,
                                                const float* __restrict__ scale_p,
                                                float* __restrict__ t) {
  const int m0 = blockIdx.x * 8;
  const int r   = threadIdx.x & 15;
  const int kcn = threadIdx.x >> 4;
  const float* ar = lA + (size_t)r * K_IN + kcn * 256;
  const float* xr = x + (size_t)m0 * K_IN + kcn * 256;
  float acc[8] = {};
  for (int k = 0; k < 256; k += 4) {
    float4 av = *(const float4*)(ar + k);
#pragma unroll
    for (int m = 0; m < 8; ++m) {
      float4 xv = *(const float4*)(xr + (size_t)m * K_IN + k);
      acc[m] += xv.x * av.x + xv.y * av.y + xv.z * av.z + xv.w * av.w;
    }
  }
  __shared__ float s[8][256];
#pragma unroll
  for (int m = 0; m < 8; ++m) s[m][threadIdx.x] = acc[m];
  __syncthreads();
  if (threadIdx.x < 128) {
    const int m = threadIdx.x >> 4, rr = threadIdx.x & 15;
    float v = 0.f;
#pragma unroll
    for (int i = 0; i < 16; ++i) v += s[m][rr + i * 16];
    t[(size_t)(m0 + m) * R_LORA + rr] = v * (*scale_p);
  }
}

// ---------------- pass 3: C = A @ Bw^T + bias + t @ lB^T — single-barrier 4-phase/tile ----------------
// Geometry/layout/swizzle identical to round 4 (512 thr = 8 waves 2Mx4N, LDS 128 KiB,
// regions by consumption quadrant, XOR-16B-slot swizzle; conflicts measured 0;
// r4 verified: WRITE 137MB no spill, MfmaUtil 45.3, 1034 TF, PASSED replay tripwires).
// ROUND-7: schedule reverted to r4's EXACT verified phase order
//   [RD(Q) | STAGE | counted vmcnt | MM(Q) | BAR]
// r5's vmcnt-after-MM variant raced intermittently (r6: first run passed, graph
// replays diverged). Raw s_barrier has no compiler memory-fence semantics; r4's
// order keeps every "memory"-clobbered wait adjacent to its barrier with only
// register-only MFMA between, which is the screened-safe arrangement (m152 rule:
// sync-structure edits need race-screening; r4's passed 3 benches of replays).
// vmcnt rotation (counted, never 0 in steady state):
//   P0: stage A0(t+1); vmcnt(4) drains B1(t)      [read @P1]
//   P1: stage B0(t+1); vmcnt(4) drains A1(t)      [read @P2]
//   P2: stage B1(t+1); no wait (6 in flight)
//   P3: stage A1(t+1); vmcnt(4) drains A0,B0(t+1) [read @next P0]
// Epilogue adds the rank-16 LoRA term: +sum_r t[row][r]*lB[col][r].
__global__ __launch_bounds__(512, 2) void gemm_bt256(const bf16_t* __restrict__ A,
                                                     const bf16_t* __restrict__ Bw,
                                                     const float* __restrict__ bias,
                                                     const float* __restrict__ tb,
                                                     const float* __restrict__ lB,
                                                     float* __restrict__ C) {
  __shared__ bf16_t sA[2 * 2 * 128 * 64];  // 64 KB
  __shared__ bf16_t sB[2 * 2 * 128 * 64];  // 64 KB

  const int tid  = threadIdx.x;
  const int wave = tid >> 6;
  const int lane = tid & 63;
  const int lr   = lane & 15;
  const int quad = lane >> 4;
  const int wr   = wave >> 2;   // 0..1 (M)
  const int wc   = wave & 3;    // 0..3 (N)

  // bijective XCD swizzle (512 blocks, 512 % 8 == 0)
  const int bid = blockIdx.x;
  const int swz = (bid & 7) * 64 + (bid >> 3);
  const int bn  = (swz & 15) * BN;   // N index [0,16)
  const int bm  = (swz >> 4) * BM;   // M index [0,32)

  // ---- staging source pointers (per-thread, inverse-swizzled column) ----
  const int t8  = tid >> 3;                         // 0..63
  const int col = ((tid & 7) ^ (t8 & 7)) * 8;       // inverse swizzle on source
  const bf16_t* pA00 = A + (size_t)(bm +   0 + t8) * K_IN + col;  // region0, L0
  const bf16_t* pA01 = A + (size_t)(bm + 128 + t8) * K_IN + col;  // region0, L1
  const bf16_t* pA10 = A + (size_t)(bm +  64 + t8) * K_IN + col;  // region1, L0
  const bf16_t* pA11 = A + (size_t)(bm + 192 + t8) * K_IN + col;  // region1, L1
  const int brl = (t8 >> 5) * 64 + (t8 & 31);
  const bf16_t* pB00 = Bw + (size_t)(bn +   0 + brl +  0) * K_IN + col;  // nh0, L0
  const bf16_t* pB01 = Bw + (size_t)(bn + 128 + brl +  0) * K_IN + col;  // nh0, L1
  const bf16_t* pB10 = Bw + (size_t)(bn +   0 + brl + 32) * K_IN + col;  // nh1, L0
  const bf16_t* pB11 = Bw + (size_t)(bn + 128 + brl + 32) * K_IN + col;  // nh1, L1

  // ---- fragment read base pointers (swizzled slot = (ksub*4+quad) ^ (lr&7)) ----
  const char* aR0 = (const char*)sA + (size_t)(wr * 64 + lr) * 128 + ((quad) ^ (lr & 7)) * 16;
  const char* aR1 = (const char*)sA + (size_t)(wr * 64 + lr) * 128 + ((4 + quad) ^ (lr & 7)) * 16;
  const char* bR0 = (const char*)sB + (size_t)(wc * 32 + lr) * 128 + ((quad) ^ (lr & 7)) * 16;
  const char* bR1 = (const char*)sB + (size_t)(wc * 32 + lr) * 128 + ((4 + quad) ^ (lr & 7)) * 16;

  floatx4 acc[8][4];
#pragma unroll
  for (int m = 0; m < 8; ++m)
#pragma unroll
    for (int n = 0; n < 4; ++n) acc[m][n] = {0.f, 0.f, 0.f, 0.f};

  // fragment register sets (statically indexed everywhere)
  bf16x8 a0[4][2], a1[4][2], bA[2][2], bB[2][2];

#define STAGE_A0(nb) do { \
    async_copy16(pA00, sA + (nb)         + wave * 512); \
    async_copy16(pA01, sA + (nb) + 4096  + wave * 512); \
    pA00 += BK; pA01 += BK; } while (0)
#define STAGE_A1(nb) do { \
    async_copy16(pA10, sA + (nb) + 8192  + wave * 512); \
    async_copy16(pA11, sA + (nb) + 12288 + wave * 512); \
    pA10 += BK; pA11 += BK; } while (0)
#define STAGE_B0(nb) do { \
    async_copy16(pB00, sB + (nb)         + wave * 512); \
    async_copy16(pB01, sB + (nb) + 4096  + wave * 512); \
    pB00 += BK; pB01 += BK; } while (0)
#define STAGE_B1(nb) do { \
    async_copy16(pB10, sB + (nb) + 8192  + wave * 512); \
    async_copy16(pB11, sB + (nb) + 12288 + wave * 512); \
    pB10 += BK; pB11 += BK; } while (0)

#define RD_A(dst, mh, bofs) do { _Pragma("unroll") for (int mm = 0; mm < 4; ++mm) { \
    dst[mm][0] = *(const bf16x8*)(aR0 + (bofs) + (mh) * 16384 + mm * 2048); \
    dst[mm][1] = *(const bf16x8*)(aR1 + (bofs) + (mh) * 16384 + mm * 2048); } } while (0)
#define RD_B(dst, nh, bofs) do { _Pragma("unroll") for (int nn = 0; nn < 2; ++nn) { \
    dst[nn][0] = *(const bf16x8*)(bR0 + (bofs) + (nh) * 16384 + nn * 2048); \
    dst[nn][1] = *(const bf16x8*)(bR1 + (bofs) + (nh) * 16384 + nn * 2048); } } while (0)

#define MM(aset, bset, mh, nh) do { \
    __builtin_amdgcn_s_setprio(1); \
    _Pragma("unroll") for (int mm = 0; mm < 4; ++mm) \
    _Pragma("unroll") for (int nn = 0; nn < 2; ++nn) { \
      acc[(mh)*4+mm][(nh)*2+nn] = __builtin_amdgcn_mfma_f32_16x16x32_bf16( \
          aset[mm][0], bset[nn][0], acc[(mh)*4+mm][(nh)*2+nn], 0, 0, 0); \
      acc[(mh)*4+mm][(nh)*2+nn] = __builtin_amdgcn_mfma_f32_16x16x32_bf16( \
          aset[mm][1], bset[nn][1], acc[(mh)*4+mm][(nh)*2+nn], 0, 0, 0); } \
    __builtin_amdgcn_s_setprio(0); } while (0)

// One K-tile: bo = current read-buffer byte offset, nb = next-buffer elem offset,
// ST = compile-time "not last tile". r4-verified order: waits BEFORE the MFMA cluster.
#define TILE(bo, nb, ST) do { \
    /* P0 */ \
    RD_A(a0, 0, bo); RD_B(bA, 0, bo); \
    if (ST) { STAGE_A0(nb); VMCNT4; } else { VMCNT2; }   /* drains B1(t) */ \
    MM(a0, bA, 0, 0); \
    BAR(); \
    /* P1 */ \
    RD_B(bB, 1, bo); \
    if (ST) { STAGE_B0(nb); VMCNT4; } else { VMCNT0; }   /* drains A1(t) */ \
    MM(a0, bB, 0, 1); \
    BAR(); \
    /* P2 */ \
    RD_A(a1, 1, bo); \
    if (ST) STAGE_B1(nb);                                /* no vmcnt: 6 in flight */ \
    MM(a1, bB, 1, 1); \
    BAR(); \
    /* P3 */ \
    if (ST) { STAGE_A1(nb); VMCNT4; }                    /* drains A0,B0(t+1) */ \
    MM(a1, bA, 1, 0); \
    BAR(); \
  } while (0)

  // ---- prologue: stage tile 0 into buf0; drain A0,B0 (B1,A1 stay in flight) ----
  STAGE_A0(0); STAGE_B0(0); STAGE_B1(0); STAGE_A1(0);
  VMCNT4;
  BAR();

  for (int t = 0; t < NT - 2; t += 2) {
    TILE(0, 16384, 1);       // even tile: read buf0, stage buf1
    TILE(32768, 0, 1);       // odd tile: read buf1, stage buf0
  }
  TILE(0, 16384, 1);         // tile NT-2
  TILE(32768, 0, 0);         // tile NT-1 (no staging; drains 2 -> 0)
#undef TILE
#undef STAGE_A0
#undef STAGE_A1
#undef STAGE_B0
#undef STAGE_B1
#undef RD_A
#undef RD_B
#undef MM

  // ---- epilogue: C[row][col] = acc + bias[col] + sum_r t[row][r]*lB[col][r] ----
#pragma unroll
  for (int n = 0; n < 4; ++n) {
    const int colc = bn + wc * 64 + n * 16 + lr;
    const float bb = bias[colc];
    const float4 lb0 = *(const float4*)(lB + (size_t)colc * R_LORA + 0);
    const float4 lb1 = *(const float4*)(lB + (size_t)colc * R_LORA + 4);
    const float4 lb2 = *(const float4*)(lB + (size_t)colc * R_LORA + 8);
    const float4 lb3 = *(const float4*)(lB + (size_t)colc * R_LORA + 12);
#pragma unroll
    for (int m = 0; m < 8; ++m) {
      const int row0 = bm + wr * 128 + m * 16 + quad * 4;
      floatx4 v = acc[m][n];
#pragma unroll
      for (int r = 0; r < 4; ++r) {
        const float* tp = tb + (size_t)(row0 + r) * R_LORA;
        const float4 t0 = *(const float4*)(tp + 0);
        const float4 t1 = *(const float4*)(tp + 4);
        const float4 t2 = *(const float4*)(tp + 8);
        const float4 t3 = *(const float4*)(tp + 12);
        float l = t0.x * lb0.x + t0.y * lb0.y + t0.z * lb0.z + t0.w * lb0.w
                + t1.x * lb1.x + t1.y * lb1.y + t1.z * lb1.z + t1.w * lb1.w
                + t2.x * lb2.x + t2.y * lb2.y + t2.z * lb2.z + t2.w * lb2.w
                + t3.x * lb3.x + t3.y * lb3.y + t3.z * lb3.z + t3.w * lb3.w;
        C[(size_t)(row0 + r) * N_OUT + colc] = v[r] + bb + l;
      }
    }
  }
}

// ---------------- fallback (workspace too small): fp32 path ----------------
__global__ __launch_bounds__(256) void lora_xa(const float* __restrict__ x,
                                               const float* __restrict__ lA,
                                               const float* __restrict__ scale_p,
                                               float* __restrict__ t) {
  int m = blockIdx.x;
  int r = threadIdx.x & 15;
  int kcn = threadIdx.x >> 4;
  float acc = 0.f;
  const float* xr = x + (size_t)m * K_IN + kcn * 256;
  const float* ar = lA + (size_t)r * K_IN + kcn * 256;
  for (int k = 0; k < 256; k += 4) {
    float4 xv = *(const float4*)(xr + k);
    float4 av = *(const float4*)(ar + k);
    acc += xv.x * av.x + xv.y * av.y + xv.z * av.z + xv.w * av.w;
  }
  __shared__ float s[256];
  s[threadIdx.x] = acc;
  __syncthreads();
  if (threadIdx.x < 16) {
    float v = 0.f;
    for (int i = 0; i < 16; ++i) v += s[threadIdx.x + i * 16];
    t[(size_t)m * 16 + threadIdx.x] = v * (*scale_p);
  }
}

__global__ __launch_bounds__(256) void gemm_f32_fb(const float* __restrict__ X,
                                                   const float* __restrict__ W,
                                                   const float* __restrict__ bias,
                                                   const float* __restrict__ t,
                                                   const float* __restrict__ lB,
                                                   float* __restrict__ C) {
  __shared__ float sX[64][17];
  __shared__ float sW[64][17];
  int tid = threadIdx.x;
  int tx = tid & 15, ty = tid >> 4;
  int m0 = blockIdx.y * 64, n0 = blockIdx.x * 64;
  int lrow = tid >> 2, lcol = (tid & 3) * 4;
  float acc[4][4] = {};
  for (int k0 = 0; k0 < K_IN; k0 += 16) {
    __syncthreads();
    float4 xv = *(const float4*)(X + (size_t)(m0 + lrow) * K_IN + k0 + lcol);
    float4 wv = *(const float4*)(W + (size_t)(n0 + lrow) * K_IN + k0 + lcol);
    sX[lrow][lcol + 0] = xv.x; sX[lrow][lcol + 1] = xv.y;
    sX[lrow][lcol + 2] = xv.z; sX[lrow][lcol + 3] = xv.w;
    sW[lrow][lcol + 0] = wv.x; sW[lrow][lcol + 1] = wv.y;
    sW[lrow][lcol + 2] = wv.z; sW[lrow][lcol + 3] = wv.w;
    __syncthreads();
#pragma unroll
    for (int kk = 0; kk < 16; ++kk) {
      float xr[4], wr[4];
#pragma unroll
      for (int i = 0; i < 4; ++i) { xr[i] = sX[ty * 4 + i][kk]; wr[i] = sW[tx * 4 + i][kk]; }
#pragma unroll
      for (int i = 0; i < 4; ++i)
#pragma unroll
        for (int j = 0; j < 4; ++j) acc[i][j] += xr[i] * wr[j];
    }
  }
  for (int j = 0; j < 4; ++j) {
    int n = n0 + tx * 4 + j;
    float bb = bias[n];
    for (int i = 0; i < 4; ++i) {
      int m = m0 + ty * 4 + i;
      float l = 0.f;
      for (int r = 0; r < R_LORA; ++r) l += t[(size_t)m * 16 + r] * lB[(size_t)n * 16 + r];
      C[(size_t)m * N_OUT + n] = acc[i][j] + bb + l;
    }
  }
}

extern "C" void kernel_launch(void* const* d_in, const int* in_sizes, int n_in,
                              void* d_out, int out_size, void* d_ws, size_t ws_size,
                              hipStream_t stream) {
  const float* x     = (const float*)d_in[0];
  const float* W     = (const float*)d_in[1];
  const float* bias  = (const float*)d_in[2];
  const float* lB    = (const float*)d_in[3];
  const float* lA    = (const float*)d_in[4];
  const float* scale = (const float*)d_in[5];
  float* out = (float*)d_out;

  const size_t x_bytes = (size_t)M_TOK * K_IN * sizeof(bf16_t);  // 64 MB
  const size_t w_bytes = (size_t)N_OUT * K_IN * sizeof(bf16_t);  // 32 MB

  if (ws_size >= x_bytes + w_bytes + T_BYTES) {
    bf16_t* xb = (bf16_t*)d_ws;
    bf16_t* wb = (bf16_t*)((char*)d_ws + x_bytes);
    float* tb  = (float*)((char*)d_ws + x_bytes + w_bytes);
    prep_cast<<<CASTX_BLOCKS + CASTW_BLOCKS, 256, 0, stream>>>(x, xb, W, wb);
    lora_xa8<<<LORA_BLOCKS, 256, 0, stream>>>(x, lA, scale, tb);
    gemm_bt256<<<(M_TOK / BM) * (N_OUT / BN), 512, 0, stream>>>(xb, wb, bias, tb, lB, out);
  } else {
    float* t = (float*)d_ws;
    lora_xa<<<M_TOK, 256, 0, stream>>>(x, lA, scale, t);
    gemm_f32_fb<<<dim3(N_OUT / 64, M_TOK / 64), 256, 0, stream>>>(x, W, bias, t, lB, out);
  }
}

// Round 8
// 498.731 us; speedup vs baseline: 4.7590x; 4.7590x over previous
//
#include <hip/hip_runtime.h>
#include <stdint.h>
#include <stddef.h>

#define M_TOK 8192
#define N_OUT 4096
#define K_IN  4096
#define R_LORA 16

// ---- 256x256 4-phase/tile GEMM geometry ----
#define BM 256
#define BN 256
#define BK 64
#define NT (K_IN / BK)          // 64 K-tiles

// fused prologue grid split (r4-verified)
#define WEFF_BLOCKS ((K_IN / 1024) * (N_OUT / 16))      // 4 * 256 = 1024
#define CAST_BLOCKS ((M_TOK * K_IN) / (8 * 256))        // 8 floats/thread -> 16384

typedef __bf16 bf16_t;
typedef __bf16 bf16x4 __attribute__((ext_vector_type(4)));
typedef __bf16 bf16x8 __attribute__((ext_vector_type(8)));
typedef float floatx4 __attribute__((ext_vector_type(4)));

// async global->LDS, 16B per lane. LDS dest must be wave-uniform base; HW adds lane*16.
__device__ inline void async_copy16(const bf16_t* g, bf16_t* l) {
  __builtin_amdgcn_global_load_lds(
      (__attribute__((address_space(1))) void*)(uintptr_t)(const void*)g,
      (__attribute__((address_space(3))) void*)l,
      16, 0, 0);
}

#define BAR()   __builtin_amdgcn_s_barrier()
#define VMCNT8  asm volatile("s_waitcnt vmcnt(8)" ::: "memory")
#define VMCNT4  asm volatile("s_waitcnt vmcnt(4)" ::: "memory")
#define VMCNT2  asm volatile("s_waitcnt vmcnt(2)" ::: "memory")
#define VMCNT0  asm volatile("s_waitcnt vmcnt(0)" ::: "memory")

// ---------------- fused prologue (r4 verbatim: cast x + Weff=W+scale*B@A) ----------------
__global__ __launch_bounds__(256) void prep_fused(
    const float* __restrict__ x, bf16_t* __restrict__ xb,
    const float* __restrict__ W, const float* __restrict__ lB,
    const float* __restrict__ lA, const float* __restrict__ scale_p,
    bf16_t* __restrict__ wb) {
  const int b = blockIdx.x;
  if (b < WEFF_BLOCKS) {
    const int kbase = (b & 3) * 1024 + threadIdx.x * 4;  // K_IN/1024 == 4
    const int o0    = (b >> 2) * 16;
    const float scale = *scale_p;

    float4 areg[R_LORA];
#pragma unroll
    for (int r = 0; r < R_LORA; ++r)
      areg[r] = *(const float4*)(lA + (size_t)r * K_IN + kbase);

    for (int oo = 0; oo < 16; ++oo) {
      const int o = o0 + oo;
      float4 w = *(const float4*)(W + (size_t)o * K_IN + kbase);
      float a0 = w.x, a1 = w.y, a2 = w.z, a3 = w.w;
#pragma unroll
      for (int r = 0; r < R_LORA; ++r) {
        float bb = lB[(size_t)o * R_LORA + r] * scale;  // block-uniform -> s_load
        a0 += bb * areg[r].x; a1 += bb * areg[r].y;
        a2 += bb * areg[r].z; a3 += bb * areg[r].w;
      }
      bf16x4 v;
      v[0] = (bf16_t)a0; v[1] = (bf16_t)a1; v[2] = (bf16_t)a2; v[3] = (bf16_t)a3;
      *(bf16x4*)(wb + (size_t)o * K_IN + kbase) = v;
    }
  } else {
    const size_t t = (size_t)(b - WEFF_BLOCKS) * 256 + threadIdx.x;
    const float4* xp = (const float4*)x + t * 2;
    float4 a0 = xp[0];
    float4 a1 = xp[1];
    bf16x8 v;
    v[0] = (bf16_t)a0.x; v[1] = (bf16_t)a0.y; v[2] = (bf16_t)a0.z; v[3] = (bf16_t)a0.w;
    v[4] = (bf16_t)a1.x; v[5] = (bf16_t)a1.y; v[6] = (bf16_t)a1.z; v[7] = (bf16_t)a1.w;
    *(bf16x8*)(xb + t * 8) = v;
  }
}

// ---------------- pass 2: C = A @ Bw^T + bias — deep-pipelined 4-phase/tile ----------------
// Geometry/layout/swizzle/epilogue identical to r4 (verified: 266us, MfmaUtil 45.3,
// WRITE 137MB, conflicts 0, replay-screened). ROUND-8 CHANGE: prefetch depth.
// r4 staged tile t+1's 4 units within tile t and drained loads only 2-3 phases old
// (~250-500cyc cover, marginal vs L2 latency -> stall at each vmcnt(4)). New schedule
// stages 1.5 tiles ahead so every drain targets loads >=5 phases (~1200cyc) old:
//   P0(t): stage B1(t+1)->nxt buf; vmcnt(8) drains B1(t)      [read @P1(t)]
//   P1(t): stage A1(t+1)->nxt buf; vmcnt(8) drains A1(t)      [read @P2(t)]
//   P2(t): stage A0(t+2)->cur buf; no wait
//   P3(t): stage B0(t+2)->cur buf; vmcnt(8) drains A0,B0(t+1) [read @P0(t+1)]
// Unit-granular double-buffer reuse: A0/B0(t+2) overwrite cur-buffer slots whose
// last ds_read was P0(t), two barriers before the P2/P3 stage issue -> safe.
// Steady in-flight 8-12 loads. Ledger (oldest->newest, entering tile t):
//   [B1(t),A1(t),A0(t+1),B0(t+1)]  -- each vmcnt(8) drains exactly the oldest unit.
// Prologue: 6 units issued (A0,B0,B1,A1 of t0; A0,B0 of t1), vmcnt(8) drains
// A0,B0(t0). Tail: tile 62 suppresses t+2 stages (P3: vmcnt(4)); tile 63 stages
// nothing (vmcnt 2 @P0, 0 @P1). Wait-before-MM arrangement preserved from r4.
__global__ __launch_bounds__(512, 2) void gemm_bt256(const bf16_t* __restrict__ A,
                                                     const bf16_t* __restrict__ Bw,
                                                     const float* __restrict__ bias,
                                                     float* __restrict__ C) {
  __shared__ bf16_t sA[2 * 2 * 128 * 64];  // 64 KB
  __shared__ bf16_t sB[2 * 2 * 128 * 64];  // 64 KB

  const int tid  = threadIdx.x;
  const int wave = tid >> 6;
  const int lane = tid & 63;
  const int lr   = lane & 15;
  const int quad = lane >> 4;
  const int wr   = wave >> 2;   // 0..1 (M)
  const int wc   = wave & 3;    // 0..3 (N)

  // bijective XCD swizzle (512 blocks, 512 % 8 == 0)
  const int bid = blockIdx.x;
  const int swz = (bid & 7) * 64 + (bid >> 3);
  const int bn  = (swz & 15) * BN;   // N index [0,16)
  const int bm  = (swz >> 4) * BM;   // M index [0,32)

  // ---- staging source pointers (per-thread, inverse-swizzled column) ----
  const int t8  = tid >> 3;                         // 0..63
  const int col = ((tid & 7) ^ (t8 & 7)) * 8;       // inverse swizzle on source
  const bf16_t* pA00 = A + (size_t)(bm +   0 + t8) * K_IN + col;  // region0, L0
  const bf16_t* pA01 = A + (size_t)(bm + 128 + t8) * K_IN + col;  // region0, L1
  const bf16_t* pA10 = A + (size_t)(bm +  64 + t8) * K_IN + col;  // region1, L0
  const bf16_t* pA11 = A + (size_t)(bm + 192 + t8) * K_IN + col;  // region1, L1
  const int brl = (t8 >> 5) * 64 + (t8 & 31);
  const bf16_t* pB00 = Bw + (size_t)(bn +   0 + brl +  0) * K_IN + col;  // nh0, L0
  const bf16_t* pB01 = Bw + (size_t)(bn + 128 + brl +  0) * K_IN + col;  // nh0, L1
  const bf16_t* pB10 = Bw + (size_t)(bn +   0 + brl + 32) * K_IN + col;  // nh1, L0
  const bf16_t* pB11 = Bw + (size_t)(bn + 128 + brl + 32) * K_IN + col;  // nh1, L1

  // ---- fragment read base pointers (swizzled slot = (ksub*4+quad) ^ (lr&7)) ----
  const char* aR0 = (const char*)sA + (size_t)(wr * 64 + lr) * 128 + ((quad) ^ (lr & 7)) * 16;
  const char* aR1 = (const char*)sA + (size_t)(wr * 64 + lr) * 128 + ((4 + quad) ^ (lr & 7)) * 16;
  const char* bR0 = (const char*)sB + (size_t)(wc * 32 + lr) * 128 + ((quad) ^ (lr & 7)) * 16;
  const char* bR1 = (const char*)sB + (size_t)(wc * 32 + lr) * 128 + ((4 + quad) ^ (lr & 7)) * 16;

  floatx4 acc[8][4];
#pragma unroll
  for (int m = 0; m < 8; ++m)
#pragma unroll
    for (int n = 0; n < 4; ++n) acc[m][n] = {0.f, 0.f, 0.f, 0.f};

  // fragment register sets (statically indexed everywhere)
  bf16x8 a0[4][2], a1[4][2], bA[2][2], bB[2][2];

#define STAGE_A0(nb) do { \
    async_copy16(pA00, sA + (nb)         + wave * 512); \
    async_copy16(pA01, sA + (nb) + 4096  + wave * 512); \
    pA00 += BK; pA01 += BK; } while (0)
#define STAGE_A1(nb) do { \
    async_copy16(pA10, sA + (nb) + 8192  + wave * 512); \
    async_copy16(pA11, sA + (nb) + 12288 + wave * 512); \
    pA10 += BK; pA11 += BK; } while (0)
#define STAGE_B0(nb) do { \
    async_copy16(pB00, sB + (nb)         + wave * 512); \
    async_copy16(pB01, sB + (nb) + 4096  + wave * 512); \
    pB00 += BK; pB01 += BK; } while (0)
#define STAGE_B1(nb) do { \
    async_copy16(pB10, sB + (nb) + 8192  + wave * 512); \
    async_copy16(pB11, sB + (nb) + 12288 + wave * 512); \
    pB10 += BK; pB11 += BK; } while (0)

#define RD_A(dst, mh, bofs) do { _Pragma("unroll") for (int mm = 0; mm < 4; ++mm) { \
    dst[mm][0] = *(const bf16x8*)(aR0 + (bofs) + (mh) * 16384 + mm * 2048); \
    dst[mm][1] = *(const bf16x8*)(aR1 + (bofs) + (mh) * 16384 + mm * 2048); } } while (0)
#define RD_B(dst, nh, bofs) do { _Pragma("unroll") for (int nn = 0; nn < 2; ++nn) { \
    dst[nn][0] = *(const bf16x8*)(bR0 + (bofs) + (nh) * 16384 + nn * 2048); \
    dst[nn][1] = *(const bf16x8*)(bR1 + (bofs) + (nh) * 16384 + nn * 2048); } } while (0)

#define MM(aset, bset, mh, nh) do { \
    __builtin_amdgcn_s_setprio(1); \
    _Pragma("unroll") for (int mm = 0; mm < 4; ++mm) \
    _Pragma("unroll") for (int nn = 0; nn < 2; ++nn) { \
      acc[(mh)*4+mm][(nh)*2+nn] = __builtin_amdgcn_mfma_f32_16x16x32_bf16( \
          aset[mm][0], bset[nn][0], acc[(mh)*4+mm][(nh)*2+nn], 0, 0, 0); \
      acc[(mh)*4+mm][(nh)*2+nn] = __builtin_amdgcn_mfma_f32_16x16x32_bf16( \
          aset[mm][1], bset[nn][1], acc[(mh)*4+mm][(nh)*2+nn], 0, 0, 0); } \
    __builtin_amdgcn_s_setprio(0); } while (0)

// Steady tile: bo = cur-buffer byte offset, eCur/eNxt = cur/next buffer elem offsets.
#define TILE(bo, eCur, eNxt) do { \
    /* P0 */ \
    RD_A(a0, 0, bo); RD_B(bA, 0, bo); \
    STAGE_B1(eNxt); VMCNT8;            /* drains B1(t), 5 phases old */ \
    MM(a0, bA, 0, 0); \
    BAR(); \
    /* P1 */ \
    RD_B(bB, 1, bo); \
    STAGE_A1(eNxt); VMCNT8;            /* drains A1(t), 5 phases old */ \
    MM(a0, bB, 0, 1); \
    BAR(); \
    /* P2 */ \
    RD_A(a1, 1, bo); \
    STAGE_A0(eCur);                    /* tile t+2, reuses cur A0 slot (last read P0) */ \
    MM(a1, bB, 1, 1); \
    BAR(); \
    /* P3 */ \
    STAGE_B0(eCur); VMCNT8;            /* drains A0,B0(t+1), 5-6 phases old */ \
    MM(a1, bA, 1, 0); \
    BAR(); \
  } while (0)

  // ---- prologue: 6 units (12 loads) in steady-state issue order ----
  STAGE_A0(0); STAGE_B0(0);            // tile0 A0,B0  (oldest)
  STAGE_B1(0); STAGE_A1(0);            // tile0 B1,A1
  STAGE_A0(16384); STAGE_B0(16384);    // tile1 A0,B0
  VMCNT8;                              // drains A0,B0(t0)
  BAR();

  for (int t = 0; t < NT - 2; t += 2) {
    TILE(0, 0, 16384);        // even tile: read buf0
    TILE(32768, 16384, 0);    // odd tile: read buf1
  }

  // ---- tile 62 (even): no t+2 stages ----
  RD_A(a0, 0, 0); RD_B(bA, 0, 0);
  STAGE_B1(16384); VMCNT8;             // drains B1(62)
  MM(a0, bA, 0, 0); BAR();
  RD_B(bB, 1, 0);
  STAGE_A1(16384); VMCNT8;             // drains A1(62)
  MM(a0, bB, 0, 1); BAR();
  RD_A(a1, 1, 0);
  MM(a1, bB, 1, 1); BAR();
  VMCNT4;                              // drains A0,B0(63); leaves B1,A1(63)
  MM(a1, bA, 1, 0); BAR();

  // ---- tile 63 (odd): no stages; drain 2 -> 0 ----
  RD_A(a0, 0, 32768); RD_B(bA, 0, 32768);
  VMCNT2;                              // drains B1(63)
  MM(a0, bA, 0, 0); BAR();
  RD_B(bB, 1, 32768);
  VMCNT0;                              // drains A1(63)
  MM(a0, bB, 0, 1); BAR();
  RD_A(a1, 1, 32768);
  MM(a1, bB, 1, 1); BAR();
  MM(a1, bA, 1, 0); BAR();
#undef TILE
#undef STAGE_A0
#undef STAGE_A1
#undef STAGE_B0
#undef STAGE_B1
#undef RD_A
#undef RD_B
#undef MM

  // ---- epilogue (r4 verbatim): C row = bm+wr*128+m*16+quad*4+r, col = bn+wc*64+n*16+lr ----
#pragma unroll
  for (int n = 0; n < 4; ++n) {
    const int colc = bn + wc * 64 + n * 16 + lr;
    const float bb = bias[colc];
#pragma unroll
    for (int m = 0; m < 8; ++m) {
      const int row0 = bm + wr * 128 + m * 16 + quad * 4;
      floatx4 v = acc[m][n];
#pragma unroll
      for (int r = 0; r < 4; ++r)
        C[(size_t)(row0 + r) * N_OUT + colc] = v[r] + bb;
    }
  }
}

// ---------------- fallback (workspace too small): fp32 path ----------------
__global__ __launch_bounds__(256) void lora_xa(const float* __restrict__ x,
                                               const float* __restrict__ lA,
                                               const float* __restrict__ scale_p,
                                               float* __restrict__ t) {
  int m = blockIdx.x;
  int r = threadIdx.x & 15;
  int kcn = threadIdx.x >> 4;
  float acc = 0.f;
  const float* xr = x + (size_t)m * K_IN + kcn * 256;
  const float* ar = lA + (size_t)r * K_IN + kcn * 256;
  for (int k = 0; k < 256; k += 4) {
    float4 xv = *(const float4*)(xr + k);
    float4 av = *(const float4*)(ar + k);
    acc += xv.x * av.x + xv.y * av.y + xv.z * av.z + xv.w * av.w;
  }
  __shared__ float s[256];
  s[threadIdx.x] = acc;
  __syncthreads();
  if (threadIdx.x < 16) {
    float v = 0.f;
    for (int i = 0; i < 16; ++i) v += s[threadIdx.x + i * 16];
    t[(size_t)m * 16 + threadIdx.x] = v * (*scale_p);
  }
}

__global__ __launch_bounds__(256) void gemm_f32_fb(const float* __restrict__ X,
                                                   const float* __restrict__ W,
                                                   const float* __restrict__ bias,
                                                   const float* __restrict__ t,
                                                   const float* __restrict__ lB,
                                                   float* __restrict__ C) {
  __shared__ float sX[64][17];
  __shared__ float sW[64][17];
  int tid = threadIdx.x;
  int tx = tid & 15, ty = tid >> 4;
  int m0 = blockIdx.y * 64, n0 = blockIdx.x * 64;
  int lrow = tid >> 2, lcol = (tid & 3) * 4;
  float acc[4][4] = {};
  for (int k0 = 0; k0 < K_IN; k0 += 16) {
    __syncthreads();
    float4 xv = *(const float4*)(X + (size_t)(m0 + lrow) * K_IN + k0 + lcol);
    float4 wv = *(const float4*)(W + (size_t)(n0 + lrow) * K_IN + k0 + lcol);
    sX[lrow][lcol + 0] = xv.x; sX[lrow][lcol + 1] = xv.y;
    sX[lrow][lcol + 2] = xv.z; sX[lrow][lcol + 3] = xv.w;
    sW[lrow][lcol + 0] = wv.x; sW[lrow][lcol + 1] = wv.y;
    sW[lrow][lcol + 2] = wv.z; sW[lrow][lcol + 3] = wv.w;
    __syncthreads();
#pragma unroll
    for (int kk = 0; kk < 16; ++kk) {
      float xr[4], wr[4];
#pragma unroll
      for (int i = 0; i < 4; ++i) { xr[i] = sX[ty * 4 + i][kk]; wr[i] = sW[tx * 4 + i][kk]; }
#pragma unroll
      for (int i = 0; i < 4; ++i)
#pragma unroll
        for (int j = 0; j < 4; ++j) acc[i][j] += xr[i] * wr[j];
    }
  }
  for (int j = 0; j < 4; ++j) {
    int n = n0 + tx * 4 + j;
    float bb = bias[n];
    for (int i = 0; i < 4; ++i) {
      int m = m0 + ty * 4 + i;
      float l = 0.f;
      for (int r = 0; r < R_LORA; ++r) l += t[(size_t)m * 16 + r] * lB[(size_t)n * 16 + r];
      C[(size_t)m * N_OUT + n] = acc[i][j] + bb + l;
    }
  }
}

extern "C" void kernel_launch(void* const* d_in, const int* in_sizes, int n_in,
                              void* d_out, int out_size, void* d_ws, size_t ws_size,
                              hipStream_t stream) {
  const float* x     = (const float*)d_in[0];
  const float* W     = (const float*)d_in[1];
  const float* bias  = (const float*)d_in[2];
  const float* lB    = (const float*)d_in[3];
  const float* lA    = (const float*)d_in[4];
  const float* scale = (const float*)d_in[5];
  float* out = (float*)d_out;

  const size_t x_bytes = (size_t)M_TOK * K_IN * sizeof(bf16_t);  // 64 MB
  const size_t w_bytes = (size_t)N_OUT * K_IN * sizeof(bf16_t);  // 32 MB

  if (ws_size >= x_bytes + w_bytes) {
    bf16_t* xb = (bf16_t*)d_ws;
    bf16_t* wb = (bf16_t*)((char*)d_ws + x_bytes);
    prep_fused<<<WEFF_BLOCKS + CAST_BLOCKS, 256, 0, stream>>>(x, xb, W, lB, lA, scale, wb);
    gemm_bt256<<<(M_TOK / BM) * (N_OUT / BN), 512, 0, stream>>>(xb, wb, bias, out);
  } else {
    float* t = (float*)d_ws;
    lora_xa<<<M_TOK, 256, 0, stream>>>(x, lA, scale, t);
    gemm_f32_fb<<<dim3(N_OUT / 64, M_TOK / 64), 256, 0, stream>>>(x, W, bias, t, lB, out);
  }
}